// Round 7
// baseline (456.751 us; speedup 1.0000x reference)
//
#include <hip/hip_runtime.h>
#include <stdint.h>

#define L_SEQ 512
#define BATCH 64
#define KTOT  512   // E + H
#define TDIM  50
#define HID2  512   // 2*H
#define ROWSTRIDE ((long)BATCH * HID2)  // floats per l-slice of hidden
#define NLOG2E 1.4426950408889634f     // P' = -log2e*(Wx+b); W' = -log2e*W_h

typedef __attribute__((ext_vector_type(8))) short bf16x8;
typedef __attribute__((ext_vector_type(4))) float f32x4;

static __device__ __forceinline__ unsigned short f2bf(float f) {
  union { float f; unsigned int u; } v; v.f = f;
  unsigned int r = (v.u + 0x7FFFu + ((v.u >> 16) & 1u)) >> 16;  // RNE
  return (unsigned short)r;
}

static __device__ __forceinline__ bf16x8 pack8(const float* f) {
  bf16x8 r;
#pragma unroll
  for (int i = 0; i < 8; ++i) r[i] = (short)f2bf(f[i]);
  return r;
}

// HW packed f32->bf16 (RNE): lo16 = bf16(a), hi16 = bf16(b)
static __device__ __forceinline__ unsigned cvt_pk_bf16(float a, float b) {
  unsigned r;
  asm("v_cvt_pk_bf16_f32 %0, %1, %2" : "=v"(r) : "v"(a), "v"(b));
  return r;
}

// LDS tile layout (16 rows x 256 k, bf16, 512 B/row):
//   byte = m*512 + ((k*2) ^ ((m&7)<<4))   (XOR swizzle, 16B granular)

// ---------------------------------------------------------------------------
// pre_kernel: P'[g][dir*256 + j] = -log2e * (emb[text] . W_dir[j][0:256] + b)
// written INTO the hidden output region (scan RMWs it in place).
// dir=1 rows are time-reversed (row l holds x[511-l] terms).
// ---------------------------------------------------------------------------
__global__ __launch_bounds__(512) void pre_kernel(
    const int* __restrict__ text, const float* __restrict__ emb,
    const float* __restrict__ W_f, const float* __restrict__ b_f,
    const float* __restrict__ W_b, const float* __restrict__ b_b,
    float* __restrict__ hidden) {
  const int blk = blockIdx.x;          // 0..511
  const int dir = blk >> 8;
  const int base = (blk & 255) * 128;  // g-row base (g = l*64 + b)
  const float* W    = dir ? W_b : W_f;
  const float* bias = dir ? b_b : b_f;
  const int tid = threadIdx.x;
  const int w = tid >> 6, ln = tid & 63, m16 = ln & 15, g4 = ln >> 4;

  __shared__ __align__(16) unsigned char xLds[16 * 512];

  // W x-part fragments: wave w owns j-range [w*32, w*32+32), K=256
  bf16x8 wfrag[2][8];
#pragma unroll
  for (int t = 0; t < 2; ++t) {
    const int j0 = w * 32 + t * 16 + m16;
#pragma unroll
    for (int kk = 0; kk < 8; ++kk) {
      const float* p = W + (long)j0 * KTOT + kk * 32 + g4 * 8;
      float4 p0 = *(const float4*)(p);
      float4 p1 = *(const float4*)(p + 4);
      float f[8] = {p0.x, p0.y, p0.z, p0.w, p1.x, p1.y, p1.z, p1.w};
      wfrag[t][kk] = pack8(f);
    }
  }
  float biasr[2][4];
#pragma unroll
  for (int t = 0; t < 2; ++t)
#pragma unroll
    for (int r = 0; r < 4; ++r) biasr[t][r] = bias[w * 32 + t * 16 + 4 * g4 + r];

  const int xm = tid >> 5;          // staged row
  const int e0 = (tid & 31) * 8;    // 8 contiguous f32 per thread

  for (int mt = 0; mt < 8; ++mt) {
    const int g = base + mt * 16 + xm;
    const int l = g >> 6, b = g & 63;
    const int srcl = dir ? (L_SEQ - 1 - l) : l;
    const int tok = text[srcl * BATCH + b];
    const float* xp = emb + (long)tok * 256 + e0;
    float4 a0 = *(const float4*)(xp);
    float4 a1 = *(const float4*)(xp + 4);
    float f[8] = {a0.x, a0.y, a0.z, a0.w, a1.x, a1.y, a1.z, a1.w};
    bf16x8 xv = pack8(f);
    if (mt) __syncthreads();  // prior tile's reads done before overwrite
    *(bf16x8*)(xLds + xm * 512 + ((e0 * 2) ^ ((xm & 7) << 4))) = xv;
    __syncthreads();

    f32x4 acc0 = {0.f, 0.f, 0.f, 0.f};
    f32x4 acc1 = {0.f, 0.f, 0.f, 0.f};
#pragma unroll
    for (int kk = 0; kk < 8; ++kk) {
      bf16x8 uf = *(const bf16x8*)(xLds + m16 * 512 +
                                   (((kk * 64) + g4 * 16) ^ ((m16 & 7) << 4)));
      acc0 = __builtin_amdgcn_mfma_f32_16x16x32_bf16(wfrag[0][kk], uf, acc0, 0, 0, 0);
      acc1 = __builtin_amdgcn_mfma_f32_16x16x32_bf16(wfrag[1][kk], uf, acc1, 0, 0, 0);
    }
    const int gg = base + mt * 16 + m16;
    float* op = hidden + (long)gg * HID2 + dir * 256 + w * 32 + 4 * g4;
    *(float4*)(op)      = make_float4(-NLOG2E * (acc0[0] + biasr[0][0]),
                                      -NLOG2E * (acc0[1] + biasr[0][1]),
                                      -NLOG2E * (acc0[2] + biasr[0][2]),
                                      -NLOG2E * (acc0[3] + biasr[0][3]));
    *(float4*)(op + 16) = make_float4(-NLOG2E * (acc1[0] + biasr[1][0]),
                                      -NLOG2E * (acc1[1] + biasr[1][1]),
                                      -NLOG2E * (acc1[2] + biasr[1][2]),
                                      -NLOG2E * (acc1[3] + biasr[1][3]));
  }
}

// ---------------------------------------------------------------------------
// scan_kernel: h' = 1/(1+exp2(P' + W'.h)), 8 WGs, 512 threads = 8 waves
// (2/SIMD), 2 j-tiles per wave, K=256.
// r7: 4 independent MFMA chains (depth 4) per wave; P' prefetched 4 steps
// ahead via 4 register sets + 4-step unroll (vmcnt waits provably free).
// One lgkmcnt(0)+s_barrier per step.
// ---------------------------------------------------------------------------
__global__ __launch_bounds__(512, 1) void scan_kernel(
    const float* __restrict__ W_f, const float* __restrict__ W_b,
    float* __restrict__ hidden) {
  const int wg  = blockIdx.x;     // 0..7
  const int dir = wg >> 2;
  const int b0  = (wg & 3) * 16;
  const int tid = threadIdx.x;
  const int w = tid >> 6, ln = tid & 63, m16 = ln & 15, g4 = ln >> 4;
  const float* W = dir ? W_b : W_f;

  __shared__ __align__(16) unsigned char hLds[2][16 * 512];

  // W h-part fragments (pre-scaled by -log2e): wave w owns j in [w*32, w*32+32)
  bf16x8 wfrag[2][8];
#pragma unroll
  for (int t = 0; t < 2; ++t) {
    const int j0 = w * 32 + t * 16 + m16;
#pragma unroll
    for (int kk = 0; kk < 8; ++kk) {
      const float* p = W + (long)j0 * KTOT + 256 + kk * 32 + g4 * 8;
      float4 p0 = *(const float4*)(p);
      float4 p1 = *(const float4*)(p + 4);
      float f[8] = {-NLOG2E * p0.x, -NLOG2E * p0.y, -NLOG2E * p0.z, -NLOG2E * p0.w,
                    -NLOG2E * p1.x, -NLOG2E * p1.y, -NLOG2E * p1.z, -NLOG2E * p1.w};
      wfrag[t][kk] = pack8(f);
    }
  }

  // hoisted LDS byte offsets
  const int swz = (m16 & 7) << 4;
  int rdoff[8];
#pragma unroll
  for (int kk = 0; kk < 8; ++kk)
    rdoff[kk] = m16 * 512 + ((kk * 64 + g4 * 16) ^ swz);
  const int wroff0 = m16 * 512 + ((w * 64 + g4 * 8) ^ swz);        // t=0
  const int wroff1 = m16 * 512 + ((w * 64 + 32 + g4 * 8) ^ swz);   // t=1

  // zero h buffer 0 (512 threads x 16 B)
  *(f32x4*)(&hLds[0][0] + tid * 16) = f32x4{0.f, 0.f, 0.f, 0.f};

  // per-lane column offset into a hidden l-slice (P' read & h write alias)
  const long roff = (long)(b0 + m16) * HID2 + dir * 256 + w * 32 + 4 * g4;

  // P' register sets: pA..pD cover steps s%4 = 0..3, refilled 4 steps ahead
  f32x4 pA0, pA1, pB0, pB1, pC0, pC1, pD0, pD1;
  pA0 = *(const f32x4*)(hidden + 0 * ROWSTRIDE + roff);
  pA1 = *(const f32x4*)(hidden + 0 * ROWSTRIDE + roff + 16);
  pB0 = *(const f32x4*)(hidden + 1 * ROWSTRIDE + roff);
  pB1 = *(const f32x4*)(hidden + 1 * ROWSTRIDE + roff + 16);
  pC0 = *(const f32x4*)(hidden + 2 * ROWSTRIDE + roff);
  pC1 = *(const f32x4*)(hidden + 2 * ROWSTRIDE + roff + 16);
  pD0 = *(const f32x4*)(hidden + 3 * ROWSTRIDE + roff);
  pD1 = *(const f32x4*)(hidden + 3 * ROWSTRIDE + roff + 16);

  __syncthreads();

// one scan step: h from hLds[BUF] -> h' into hLds[BUF^1]; store row SROW;
// refill (PF0,PF1) with P'[SROW+4] at the end (clamped at tail, unused).
// 4 independent MFMA chains (a0a/a0b/a1a/a1b), depth 4 each.
#define STEP(BUF, PF0, PF1, SROW)                                              \
  {                                                                            \
    bf16x8 uf[8];                                                              \
    _Pragma("unroll")                                                          \
    for (int kk = 0; kk < 8; ++kk)                                             \
      uf[kk] = *(const bf16x8*)(&hLds[BUF][0] + rdoff[kk]);                    \
    f32x4 a0a = {0.f, 0.f, 0.f, 0.f}, a0b = {0.f, 0.f, 0.f, 0.f};              \
    f32x4 a1a = {0.f, 0.f, 0.f, 0.f}, a1b = {0.f, 0.f, 0.f, 0.f};              \
    _Pragma("unroll")                                                          \
    for (int kk = 0; kk < 4; ++kk) {                                           \
      a0a = __builtin_amdgcn_mfma_f32_16x16x32_bf16(wfrag[0][2 * kk],          \
                                                    uf[2 * kk], a0a, 0, 0, 0); \
      a1a = __builtin_amdgcn_mfma_f32_16x16x32_bf16(wfrag[1][2 * kk],          \
                                                    uf[2 * kk], a1a, 0, 0, 0); \
      a0b = __builtin_amdgcn_mfma_f32_16x16x32_bf16(wfrag[0][2 * kk + 1],      \
                                                    uf[2 * kk + 1], a0b, 0, 0, \
                                                    0);                        \
      a1b = __builtin_amdgcn_mfma_f32_16x16x32_bf16(wfrag[1][2 * kk + 1],      \
                                                    uf[2 * kk + 1], a1b, 0, 0, \
                                                    0);                        \
    }                                                                          \
    float h0[4], h1[4];                                                        \
    _Pragma("unroll")                                                          \
    for (int r = 0; r < 4; ++r) {                                              \
      h0[r] = __builtin_amdgcn_rcpf(                                           \
          1.f + __builtin_amdgcn_exp2f(a0a[r] + a0b[r] + PF0[r]));             \
      h1[r] = __builtin_amdgcn_rcpf(                                           \
          1.f + __builtin_amdgcn_exp2f(a1a[r] + a1b[r] + PF1[r]));             \
    }                                                                          \
    *(uint2*)(&hLds[(BUF) ^ 1][0] + wroff0) =                                  \
        make_uint2(cvt_pk_bf16(h0[0], h0[1]), cvt_pk_bf16(h0[2], h0[3]));      \
    *(uint2*)(&hLds[(BUF) ^ 1][0] + wroff1) =                                  \
        make_uint2(cvt_pk_bf16(h1[0], h1[1]), cvt_pk_bf16(h1[2], h1[3]));      \
    float* gp = hidden + (long)(SROW)*ROWSTRIDE + roff;                        \
    *(float4*)(gp)      = make_float4(h0[0], h0[1], h0[2], h0[3]);             \
    *(float4*)(gp + 16) = make_float4(h1[0], h1[1], h1[2], h1[3]);             \
    {                                                                          \
      const long rn = ((SROW) + 4 < L_SEQ) ? (SROW) + 4 : L_SEQ - 1;           \
      const float* lp = hidden + rn * ROWSTRIDE + roff;                        \
      PF0 = *(const f32x4*)(lp);                                               \
      PF1 = *(const f32x4*)(lp + 16);                                          \
    }                                                                          \
    asm volatile("s_waitcnt lgkmcnt(0)" ::: "memory");                         \
    __builtin_amdgcn_s_barrier();                                              \
    asm volatile("" ::: "memory");                                             \
  }

  for (int s = 0; s < L_SEQ; s += 4) {
    STEP(0, pA0, pA1, s)
    STEP(1, pB0, pB1, s + 1)
    STEP(0, pC0, pC1, s + 2)
    STEP(1, pD0, pD1, s + 3)
  }
#undef STEP
}

// ---------------------------------------------------------------------------
// out[lb][t] = hidden[lb][:] . W_out[t][:] + b_out[t]
// ---------------------------------------------------------------------------
__global__ __launch_bounds__(64) void out_kernel(
    const float* __restrict__ hidden, const float* __restrict__ W_out,
    const float* __restrict__ b_out, float* __restrict__ out) {
  const int m0 = blockIdx.x * 16;
  const int ln = threadIdx.x;
  const int m16 = ln & 15, g4 = ln >> 4;

  bf16x8 a[16];
  const float* hp = hidden + (long)(m0 + m16) * HID2 + g4 * 8;
#pragma unroll
  for (int kk = 0; kk < 16; ++kk) {
    float4 p0 = *(const float4*)(hp + kk * 32);
    float4 p1 = *(const float4*)(hp + kk * 32 + 4);
    float f[8] = {p0.x, p0.y, p0.z, p0.w, p1.x, p1.y, p1.z, p1.w};
    a[kk] = pack8(f);
  }
#pragma unroll
  for (int nt = 0; nt < 4; ++nt) {
    const int trow = nt * 16 + m16;
    const bool valid = trow < TDIM;
    f32x4 acc = {0.f, 0.f, 0.f, 0.f};
    const float* wp = W_out + (long)trow * HID2 + g4 * 8;
#pragma unroll
    for (int kk = 0; kk < 16; ++kk) {
      bf16x8 bf;
      if (valid) {
        float4 p0 = *(const float4*)(wp + kk * 32);
        float4 p1 = *(const float4*)(wp + kk * 32 + 4);
        float f[8] = {p0.x, p0.y, p0.z, p0.w, p1.x, p1.y, p1.z, p1.w};
        bf = pack8(f);
      } else {
#pragma unroll
        for (int i = 0; i < 8; ++i) bf[i] = 0;
      }
      acc = __builtin_amdgcn_mfma_f32_16x16x32_bf16(a[kk], bf, acc, 0, 0, 0);
    }
    if (valid) {
      float bo = b_out[trow];
#pragma unroll
      for (int r = 0; r < 4; ++r)
        out[(long)(m0 + 4 * g4 + r) * TDIM + trow] = acc[r] + bo;
    }
  }
}

extern "C" void kernel_launch(void* const* d_in, const int* in_sizes, int n_in,
                              void* d_out, int out_size, void* d_ws, size_t ws_size,
                              hipStream_t stream) {
  const int*   text  = (const int*)d_in[0];
  const float* emb   = (const float*)d_in[1];
  const float* W_f   = (const float*)d_in[2];
  const float* b_f   = (const float*)d_in[3];
  const float* W_b   = (const float*)d_in[4];
  const float* b_b   = (const float*)d_in[5];
  const float* W_out = (const float*)d_in[6];
  const float* b_out = (const float*)d_in[7];
  float* out    = (float*)d_out;
  float* hidden = out + (long)L_SEQ * BATCH * TDIM;  // second tuple output

  pre_kernel<<<512, 512, 0, stream>>>(text, emb, W_f, b_f, W_b, b_b, hidden);
  scan_kernel<<<8, 512, 0, stream>>>(W_f, W_b, hidden);
  out_kernel<<<2048, 64, 0, stream>>>(hidden, W_out, b_out, out);
}

// Round 8
// 445.990 us; speedup vs baseline: 1.0241x; 1.0241x over previous
//
#include <hip/hip_runtime.h>
#include <stdint.h>

#define L_SEQ 512
#define BATCH 64
#define KTOT  512   // E + H
#define TDIM  50
#define HID2  512   // 2*H
#define ROWSTRIDE ((long)BATCH * HID2)  // floats per l-slice of hidden
#define NLOG2E 1.4426950408889634f     // P' = -log2e*(Wx+b); W' = -log2e*W_h

typedef __attribute__((ext_vector_type(8))) short bf16x8;
typedef __attribute__((ext_vector_type(4))) float f32x4;

static __device__ __forceinline__ unsigned short f2bf(float f) {
  union { float f; unsigned int u; } v; v.f = f;
  unsigned int r = (v.u + 0x7FFFu + ((v.u >> 16) & 1u)) >> 16;  // RNE
  return (unsigned short)r;
}

static __device__ __forceinline__ bf16x8 pack8(const float* f) {
  bf16x8 r;
#pragma unroll
  for (int i = 0; i < 8; ++i) r[i] = (short)f2bf(f[i]);
  return r;
}

// HW packed f32->bf16 (RNE): lo16 = bf16(a), hi16 = bf16(b)
static __device__ __forceinline__ unsigned cvt_pk_bf16(float a, float b) {
  unsigned r;
  asm("v_cvt_pk_bf16_f32 %0, %1, %2" : "=v"(r) : "v"(a), "v"(b));
  return r;
}

// ---------------------------------------------------------------------------
// pre_kernel: P'[g][dir*256 + j] = -log2e * (emb[text] . W_dir[j][0:256] + b)
// written INTO the hidden output region (scan RMWs it in place).
// dir=1 rows are time-reversed (row l holds x[511-l] terms).
// (unchanged from r6; keeps its own [row][k]+XOR layout for the x tile)
// ---------------------------------------------------------------------------
__global__ __launch_bounds__(512) void pre_kernel(
    const int* __restrict__ text, const float* __restrict__ emb,
    const float* __restrict__ W_f, const float* __restrict__ b_f,
    const float* __restrict__ W_b, const float* __restrict__ b_b,
    float* __restrict__ hidden) {
  const int blk = blockIdx.x;          // 0..511
  const int dir = blk >> 8;
  const int base = (blk & 255) * 128;  // g-row base (g = l*64 + b)
  const float* W    = dir ? W_b : W_f;
  const float* bias = dir ? b_b : b_f;
  const int tid = threadIdx.x;
  const int w = tid >> 6, ln = tid & 63, m16 = ln & 15, g4 = ln >> 4;

  __shared__ __align__(16) unsigned char xLds[16 * 512];

  // W x-part fragments: wave w owns j-range [w*32, w*32+32), K=256
  bf16x8 wfrag[2][8];
#pragma unroll
  for (int t = 0; t < 2; ++t) {
    const int j0 = w * 32 + t * 16 + m16;
#pragma unroll
    for (int kk = 0; kk < 8; ++kk) {
      const float* p = W + (long)j0 * KTOT + kk * 32 + g4 * 8;
      float4 p0 = *(const float4*)(p);
      float4 p1 = *(const float4*)(p + 4);
      float f[8] = {p0.x, p0.y, p0.z, p0.w, p1.x, p1.y, p1.z, p1.w};
      wfrag[t][kk] = pack8(f);
    }
  }
  float biasr[2][4];
#pragma unroll
  for (int t = 0; t < 2; ++t)
#pragma unroll
    for (int r = 0; r < 4; ++r) biasr[t][r] = bias[w * 32 + t * 16 + 4 * g4 + r];

  const int xm = tid >> 5;          // staged row
  const int e0 = (tid & 31) * 8;    // 8 contiguous f32 per thread

  for (int mt = 0; mt < 8; ++mt) {
    const int g = base + mt * 16 + xm;
    const int l = g >> 6, b = g & 63;
    const int srcl = dir ? (L_SEQ - 1 - l) : l;
    const int tok = text[srcl * BATCH + b];
    const float* xp = emb + (long)tok * 256 + e0;
    float4 a0 = *(const float4*)(xp);
    float4 a1 = *(const float4*)(xp + 4);
    float f[8] = {a0.x, a0.y, a0.z, a0.w, a1.x, a1.y, a1.z, a1.w};
    bf16x8 xv = pack8(f);
    if (mt) __syncthreads();  // prior tile's reads done before overwrite
    *(bf16x8*)(xLds + xm * 512 + ((e0 * 2) ^ ((xm & 7) << 4))) = xv;
    __syncthreads();

    f32x4 acc0 = {0.f, 0.f, 0.f, 0.f};
    f32x4 acc1 = {0.f, 0.f, 0.f, 0.f};
#pragma unroll
    for (int kk = 0; kk < 8; ++kk) {
      bf16x8 uf = *(const bf16x8*)(xLds + m16 * 512 +
                                   (((kk * 64) + g4 * 16) ^ ((m16 & 7) << 4)));
      acc0 = __builtin_amdgcn_mfma_f32_16x16x32_bf16(wfrag[0][kk], uf, acc0, 0, 0, 0);
      acc1 = __builtin_amdgcn_mfma_f32_16x16x32_bf16(wfrag[1][kk], uf, acc1, 0, 0, 0);
    }
    const int gg = base + mt * 16 + m16;
    float* op = hidden + (long)gg * HID2 + dir * 256 + w * 32 + 4 * g4;
    *(float4*)(op)      = make_float4(-NLOG2E * (acc0[0] + biasr[0][0]),
                                      -NLOG2E * (acc0[1] + biasr[0][1]),
                                      -NLOG2E * (acc0[2] + biasr[0][2]),
                                      -NLOG2E * (acc0[3] + biasr[0][3]));
    *(float4*)(op + 16) = make_float4(-NLOG2E * (acc1[0] + biasr[1][0]),
                                      -NLOG2E * (acc1[1] + biasr[1][1]),
                                      -NLOG2E * (acc1[2] + biasr[1][2]),
                                      -NLOG2E * (acc1[3] + biasr[1][3]));
  }
}

// ---------------------------------------------------------------------------
// scan_kernel: h' = 1/(1+exp2(P' + W'.h)), 8 WGs, 512 threads = 8 waves
// (2/SIMD), 2 j-tiles per wave, K=256.
// r8: h stored in B-FRAGMENT-LINEAR layout hLds[kk][lane][16B]:
//   read  uf[kk] at  kk*1024 + ln*16            (contiguous 1KB/instr)
//   write h'(t)  at  w*1024 + (t*2+(g4>>1))*256 + m16*16 + (g4&1)*8
//                                               (contiguous 512B/instr)
// Both patterns bank-coalesce -> conflict-free. No swizzle.
// P' prefetched 2 steps ahead (refill issued last), lgkmcnt-only barrier.
// ---------------------------------------------------------------------------
__global__ __launch_bounds__(512, 1) void scan_kernel(
    const float* __restrict__ W_f, const float* __restrict__ W_b,
    float* __restrict__ hidden) {
  const int wg  = blockIdx.x;     // 0..7
  const int dir = wg >> 2;
  const int b0  = (wg & 3) * 16;
  const int tid = threadIdx.x;
  const int w = tid >> 6, ln = tid & 63, m16 = ln & 15, g4 = ln >> 4;
  const float* W = dir ? W_b : W_f;

  __shared__ __align__(16) unsigned char hLds[2][8 * 1024];

  // W h-part fragments (pre-scaled by -log2e): wave w owns j in [w*32, w*32+32)
  bf16x8 wfrag[2][8];
#pragma unroll
  for (int t = 0; t < 2; ++t) {
    const int j0 = w * 32 + t * 16 + m16;
#pragma unroll
    for (int kk = 0; kk < 8; ++kk) {
      const float* p = W + (long)j0 * KTOT + 256 + kk * 32 + g4 * 8;
      float4 p0 = *(const float4*)(p);
      float4 p1 = *(const float4*)(p + 4);
      float f[8] = {-NLOG2E * p0.x, -NLOG2E * p0.y, -NLOG2E * p0.z, -NLOG2E * p0.w,
                    -NLOG2E * p1.x, -NLOG2E * p1.y, -NLOG2E * p1.z, -NLOG2E * p1.w};
      wfrag[t][kk] = pack8(f);
    }
  }

  // fragment-linear LDS offsets
  int rdoff[8];
#pragma unroll
  for (int kk = 0; kk < 8; ++kk) rdoff[kk] = kk * 1024 + ln * 16;
  const int wroff0 = w * 1024 + ((g4 >> 1) * 256) + m16 * 16 + (g4 & 1) * 8;  // t=0
  const int wroff1 = wroff0 + 512;                                            // t=1

  // zero h buffer 0 (512 threads x 16 B = 8 KB)
  *(f32x4*)(&hLds[0][0] + tid * 16) = f32x4{0.f, 0.f, 0.f, 0.f};

  // per-lane column offset into a hidden l-slice (P' read & h write alias)
  const long roff = (long)(b0 + m16) * HID2 + dir * 256 + w * 32 + 4 * g4;

  f32x4 pA0, pA1, pB0, pB1;           // P' regs: A = even steps, B = odd
  pA0 = *(const f32x4*)(hidden + roff);
  pA1 = *(const f32x4*)(hidden + roff + 16);
  pB0 = *(const f32x4*)(hidden + ROWSTRIDE + roff);
  pB1 = *(const f32x4*)(hidden + ROWSTRIDE + roff + 16);

  __syncthreads();

// one scan step: h from hLds[BUF] -> h' into hLds[BUF^1]; store row SROW;
// refill (PF0,PF1) with P'[SROW+2] at the very end (clamped at tail).
#define STEP(BUF, PF0, PF1, SROW)                                              \
  {                                                                            \
    bf16x8 uf[8];                                                              \
    _Pragma("unroll")                                                          \
    for (int kk = 0; kk < 8; ++kk)                                             \
      uf[kk] = *(const bf16x8*)(&hLds[BUF][0] + rdoff[kk]);                    \
    f32x4 acc0 = {0.f, 0.f, 0.f, 0.f};                                         \
    f32x4 acc1 = {0.f, 0.f, 0.f, 0.f};                                         \
    _Pragma("unroll")                                                          \
    for (int kk = 0; kk < 8; ++kk) {                                           \
      acc0 = __builtin_amdgcn_mfma_f32_16x16x32_bf16(wfrag[0][kk], uf[kk],     \
                                                     acc0, 0, 0, 0);           \
      acc1 = __builtin_amdgcn_mfma_f32_16x16x32_bf16(wfrag[1][kk], uf[kk],     \
                                                     acc1, 0, 0, 0);           \
    }                                                                          \
    float h0[4], h1[4];                                                        \
    _Pragma("unroll")                                                          \
    for (int r = 0; r < 4; ++r) {                                              \
      h0[r] = __builtin_amdgcn_rcpf(                                           \
          1.f + __builtin_amdgcn_exp2f(acc0[r] + PF0[r]));                     \
      h1[r] = __builtin_amdgcn_rcpf(                                           \
          1.f + __builtin_amdgcn_exp2f(acc1[r] + PF1[r]));                     \
    }                                                                          \
    *(uint2*)(&hLds[(BUF) ^ 1][0] + wroff0) =                                  \
        make_uint2(cvt_pk_bf16(h0[0], h0[1]), cvt_pk_bf16(h0[2], h0[3]));      \
    *(uint2*)(&hLds[(BUF) ^ 1][0] + wroff1) =                                  \
        make_uint2(cvt_pk_bf16(h1[0], h1[1]), cvt_pk_bf16(h1[2], h1[3]));      \
    float* gp = hidden + (long)(SROW)*ROWSTRIDE + roff;                        \
    *(float4*)(gp)      = make_float4(h0[0], h0[1], h0[2], h0[3]);             \
    *(float4*)(gp + 16) = make_float4(h1[0], h1[1], h1[2], h1[3]);             \
    {                                                                          \
      const long rn = ((SROW) + 2 < L_SEQ) ? (SROW) + 2 : L_SEQ - 1;           \
      const float* lp = hidden + rn * ROWSTRIDE + roff;                        \
      PF0 = *(const f32x4*)(lp);                                               \
      PF1 = *(const f32x4*)(lp + 16);                                          \
    }                                                                          \
    asm volatile("s_waitcnt lgkmcnt(0)" ::: "memory");                         \
    __builtin_amdgcn_s_barrier();                                              \
    asm volatile("" ::: "memory");                                             \
  }

  for (int s = 0; s < L_SEQ; s += 2) {
    STEP(0, pA0, pA1, s)
    STEP(1, pB0, pB1, s + 1)
  }
#undef STEP
}

// ---------------------------------------------------------------------------
// out[lb][t] = hidden[lb][:] . W_out[t][:] + b_out[t]
// ---------------------------------------------------------------------------
__global__ __launch_bounds__(64) void out_kernel(
    const float* __restrict__ hidden, const float* __restrict__ W_out,
    const float* __restrict__ b_out, float* __restrict__ out) {
  const int m0 = blockIdx.x * 16;
  const int ln = threadIdx.x;
  const int m16 = ln & 15, g4 = ln >> 4;

  bf16x8 a[16];
  const float* hp = hidden + (long)(m0 + m16) * HID2 + g4 * 8;
#pragma unroll
  for (int kk = 0; kk < 16; ++kk) {
    float4 p0 = *(const float4*)(hp + kk * 32);
    float4 p1 = *(const float4*)(hp + kk * 32 + 4);
    float f[8] = {p0.x, p0.y, p0.z, p0.w, p1.x, p1.y, p1.z, p1.w};
    a[kk] = pack8(f);
  }
#pragma unroll
  for (int nt = 0; nt < 4; ++nt) {
    const int trow = nt * 16 + m16;
    const bool valid = trow < TDIM;
    f32x4 acc = {0.f, 0.f, 0.f, 0.f};
    const float* wp = W_out + (long)trow * HID2 + g4 * 8;
#pragma unroll
    for (int kk = 0; kk < 16; ++kk) {
      bf16x8 bf;
      if (valid) {
        float4 p0 = *(const float4*)(wp + kk * 32);
        float4 p1 = *(const float4*)(wp + kk * 32 + 4);
        float f[8] = {p0.x, p0.y, p0.z, p0.w, p1.x, p1.y, p1.z, p1.w};
        bf = pack8(f);
      } else {
#pragma unroll
        for (int i = 0; i < 8; ++i) bf[i] = 0;
      }
      acc = __builtin_amdgcn_mfma_f32_16x16x32_bf16(a[kk], bf, acc, 0, 0, 0);
    }
    if (valid) {
      float bo = b_out[trow];
#pragma unroll
      for (int r = 0; r < 4; ++r)
        out[(long)(m0 + 4 * g4 + r) * TDIM + trow] = acc[r] + bo;
    }
  }
}

extern "C" void kernel_launch(void* const* d_in, const int* in_sizes, int n_in,
                              void* d_out, int out_size, void* d_ws, size_t ws_size,
                              hipStream_t stream) {
  const int*   text  = (const int*)d_in[0];
  const float* emb   = (const float*)d_in[1];
  const float* W_f   = (const float*)d_in[2];
  const float* b_f   = (const float*)d_in[3];
  const float* W_b   = (const float*)d_in[4];
  const float* b_b   = (const float*)d_in[5];
  const float* W_out = (const float*)d_in[6];
  const float* b_out = (const float*)d_in[7];
  float* out    = (float*)d_out;
  float* hidden = out + (long)L_SEQ * BATCH * TDIM;  // second tuple output

  pre_kernel<<<512, 512, 0, stream>>>(text, emb, W_f, b_f, W_b, b_b, hidden);
  scan_kernel<<<8, 512, 0, stream>>>(W_f, W_b, hidden);
  out_kernel<<<2048, 64, 0, stream>>>(hidden, W_out, b_out, out);
}